// Round 1
// baseline (437.684 us; speedup 1.0000x reference)
//
#include <hip/hip_runtime.h>
#include <hip/hip_bf16.h>
#include <math.h>

// Problem constants (match reference)
#define T_TOK 1024
#define H_DIM 1024
#define I_DIM 512
#define E_NUM 32
#define K_TOP 4
#define G_NUM 8
#define TG_NUM 4
#define CAP 256              // C = 2*T*K/E
#define IS_DIM 1024          // I * NS
#define RSCALE 2.5f

#define MAXTILES 36          // 4 shared (256-row) + <=32 routed (one per expert)

// ws layout (byte offsets)
#define WS_CNT_OFF    0          // int cnt[32]
#define WS_NT_OFF     128        // int ntiles
#define WS_TILE_OFF   256        // int tiles[MAXTILES][4] = (e, r0, ne, pad)
#define WS_EIDX_OFF   4096       // int eidx[T*K]
#define WS_WN_OFF     20480      // float wnorm[T*K]
#define WS_STOK_OFF   36864      // int slot_token[E*CAP]
#define WS_SW_OFF     69632      // float slot_w[E*CAP]
#define WS_ACT_OFF    102400     // bf16 act[E*CAP*I]  (8 MB)
#define WS_ACTS_OFF   (102400 + (size_t)E_NUM*CAP*I_DIM*2)   // bf16 acts[T*IS] (2 MB)
#define WS_XB_OFF     (WS_ACTS_OFF + (size_t)T_TOK*IS_DIM*2) // bf16 xb[T*H]    (2 MB)

typedef __attribute__((ext_vector_type(8))) short short8v;
typedef __attribute__((ext_vector_type(4))) float f32x4;
typedef __attribute__((ext_vector_type(4))) unsigned uint4v;

__device__ __forceinline__ short f2bf(float f) {          // RNE, epilogue only
    unsigned u = __float_as_uint(f);
    u += 0x7FFFu + ((u >> 16) & 1u);
    return (short)(u >> 16);
}
// pack 2 floats -> 2 bf16 (round-half-up): 3 VALU ops
__device__ __forceinline__ unsigned pk2bf(float a, float b) {
    unsigned ua = __float_as_uint(a) + 0x8000u;
    unsigned ub = __float_as_uint(b) + 0x8000u;
    return __builtin_amdgcn_perm(ub, ua, 0x07060302);      // lo short=bf(a), hi=bf(b)
}
__device__ __forceinline__ uint4v pk8bf(float4 lo, float4 hi) {
    uint4v r; r.x = pk2bf(lo.x, lo.y); r.y = pk2bf(lo.z, lo.w);
    r.z = pk2bf(hi.x, hi.y); r.w = pk2bf(hi.z, hi.w); return r;
}
__device__ __forceinline__ float silu_(float g) { return g / (1.f + expf(-g)); }

#define LDSTRIDE 40   // shorts per LDS row (80 B, keeps b128 writes aligned)

// -------- gating (also emits bf16 copy of x for GEMM A-operand) --------
__global__ __launch_bounds__(256) void gate_kernel(
    const float* __restrict__ x, const float* __restrict__ gate_w,
    const float* __restrict__ e_bias,
    int* __restrict__ eidx, float* __restrict__ wnorm, short* __restrict__ xb)
{
    __shared__ float xs[H_DIM];
    __shared__ float logits[E_NUM];
    const int t = blockIdx.x;
    const int tid = threadIdx.x;
    float4 v = ((const float4*)(x + (size_t)t * H_DIM))[tid];
    ((float4*)xs)[tid] = v;
    {   // bf16 copy of this token's row (same rounding as GEMM staging used)
        unsigned* xd = (unsigned*)(xb + (size_t)t * H_DIM) + tid * 2;
        xd[0] = pk2bf(v.x, v.y); xd[1] = pk2bf(v.z, v.w);
    }
    __syncthreads();

    const int e = tid >> 3, sub = tid & 7;   // 32 experts x 8 threads
    const float4* gw4 = (const float4*)(gate_w + (size_t)e * H_DIM + sub * 128);
    const float4* xr4 = (const float4*)(xs + sub * 128);
    float p = 0.f;
    #pragma unroll
    for (int h = 0; h < 32; ++h) {
        float4 a = xr4[h], b = gw4[h];
        p += a.x * b.x + a.y * b.y + a.z * b.z + a.w * b.w;
    }
    for (int off = 4; off; off >>= 1) p += __shfl_down(p, off, 8);
    if (sub == 0) logits[e] = p;
    __syncthreads();
    if (tid != 0) return;

    float sc[E_NUM], sfc[E_NUM];
    for (int i = 0; i < E_NUM; ++i) {
        sc[i] = 1.f / (1.f + expf(-logits[i]));
        sfc[i] = sc[i] + e_bias[i];
    }
    float gs[G_NUM];
    for (int g = 0; g < G_NUM; ++g) {
        float m1 = -1e30f, m2 = -1e30f;
        for (int j = 0; j < E_NUM / G_NUM; ++j) {
            float v2 = sfc[g * (E_NUM / G_NUM) + j];
            if (v2 > m1) { m2 = m1; m1 = v2; } else if (v2 > m2) m2 = v2;
        }
        gs[g] = m1 + m2;
    }
    bool gm[G_NUM];
    for (int g = 0; g < G_NUM; ++g) gm[g] = false;
    for (int it = 0; it < TG_NUM; ++it) {
        int best = -1; float bv = -1e30f;
        for (int g = 0; g < G_NUM; ++g) if (!gm[g] && gs[g] > bv) { bv = gs[g]; best = g; }
        gm[best] = true;
    }
    float sm[E_NUM];
    for (int i = 0; i < E_NUM; ++i) sm[i] = gm[i / (E_NUM / G_NUM)] ? sfc[i] : 0.0f;
    int idx[K_TOP]; float w[K_TOP]; float tsum = 0.f;
    for (int it = 0; it < K_TOP; ++it) {
        int best = 0; float bv = -1e30f;
        for (int i = 0; i < E_NUM; ++i) if (sm[i] > bv) { bv = sm[i]; best = i; }
        sm[best] = -1e30f;
        idx[it] = best; w[it] = sc[best]; tsum += w[it];
    }
    float inv = RSCALE / (tsum + 1e-20f);
    const int base = t * K_TOP;
    for (int it = 0; it < K_TOP; ++it) {
        eidx[base + it] = idx[it];
        wnorm[base + it] = w[it] * inv;
    }
}

// -------- deterministic capacity dispatch + tile-list (one tile per expert) ----
__global__ __launch_bounds__(256) void assign_kernel(
    const int* __restrict__ eidx, const float* __restrict__ wnorm,
    int* __restrict__ cnt, int* __restrict__ slot_token, float* __restrict__ slot_w,
    int* __restrict__ ntiles, int* __restrict__ tiles)
{
    __shared__ int   se[T_TOK * K_TOP];
    __shared__ float swt[T_TOK * K_TOP];
    __shared__ int   scnt[E_NUM];
    const int tid = threadIdx.x;
    for (int i = tid; i < T_TOK * K_TOP; i += 256) { se[i] = eidx[i]; swt[i] = wnorm[i]; }
    __syncthreads();

    const int e = tid >> 3;
    const int seg = tid & 7;
    const int base = seg * 512;
    int c = 0;
    for (int i = 0; i < 512; ++i) c += (se[base + i] == e);
    int excl = 0, total = 0;
    for (int s = 0; s < 8; ++s) {
        int cs = __shfl(c, s, 8);
        total += cs;
        if (s < seg) excl += cs;
    }
    if (seg == 0) { cnt[e] = total; scnt[e] = total; }
    int pos = excl;
    for (int i = 0; i < 512; ++i) {
        if (se[base + i] == e) {
            if (pos < CAP) {
                slot_token[e * CAP + pos] = (base + i) >> 2;
                slot_w[e * CAP + pos] = swt[base + i];
            }
            ++pos;
        }
    }
    __syncthreads();
    if (tid == 0) {
        int nt = 0;
        // shared-expert tiles first (heaviest -> dispatched first)
        for (int t0 = 0; t0 < T_TOK; t0 += 256) {
            tiles[nt * 4] = -1; tiles[nt * 4 + 1] = t0; tiles[nt * 4 + 2] = 256; ++nt;
        }
        // one tile per routed expert: whole expert (<=256 rows, chunked in-kernel)
        for (int ee = 0; ee < E_NUM; ++ee) {
            int n = min(scnt[ee], CAP);
            if (n > 0) { tiles[nt * 4] = ee; tiles[nt * 4 + 1] = 0; tiles[nt * 4 + 2] = n; ++nt; }
        }
        *ntiles = nt;
    }
}

// ---------------- MFMA GEMM: block tile 256(M, chunked) x 128(B-rows), BK=32 ----
// 512 threads = 8 waves: wm=wid&3 owns M-chunk wm (64 rows), wn=wid>>2 owns 64 B-rows.
// B panel is read exactly ONCE per (tile, col-block).

// gate_up + SiLU*mul for routed (+slot_w) AND shared experts. grid (16, MAXTILES)
__global__ __launch_bounds__(512, 2) void gu_all_kernel(
    const short* __restrict__ xb, const float* __restrict__ w_gate_up,
    const float* __restrict__ w_gus,
    const int* __restrict__ ntiles, const int* __restrict__ tiles,
    const int* __restrict__ slot_token, const float* __restrict__ slot_w,
    short* __restrict__ act, short* __restrict__ acts)
{
    if ((int)blockIdx.y >= *ntiles) return;
    const int e  = tiles[blockIdx.y * 4];
    const int r0 = tiles[blockIdx.y * 4 + 1];
    const int ne = tiles[blockIdx.y * 4 + 2];
    const bool sh = (e < 0);
    if (!sh && blockIdx.x >= I_DIM / 64) return;
    const int col0 = blockIdx.x * 64;
    const int mchunks = (ne + 63) >> 6;        // 1..4 chunks of 64 rows
    const int rows = mchunks << 6;

    __shared__ __align__(16) short As[2][256 * LDSTRIDE];
    __shared__ __align__(16) short Bs[2][128 * LDSTRIDE];
    __shared__ int   toks[256];
    __shared__ float sws[256];

    const int tid = threadIdx.x;
    const int lane = tid & 63, wid = tid >> 6;
    const int wm = wid & 3, wn = wid >> 2;
    const int lr16 = lane & 15, kc = lane >> 4;
    const int sc_ = tid & 3, srow = tid >> 2;  // staging: 8-elem chunk, row 0..127

    if (tid < 256) {
        if (sh) { toks[tid] = r0 + tid; sws[tid] = 1.f; }
        else {
            bool v = tid < ne;
            toks[tid] = v ? slot_token[e * CAP + tid] : 0;
            sws[tid]  = v ? slot_w[e * CAP + tid] : 0.f;
        }
    }
    __syncthreads();

    const int IDim = sh ? IS_DIM : I_DIM;
    const float* wbase = sh ? w_gus : (w_gate_up + (size_t)e * (2 * I_DIM) * H_DIM);
    // B-row c -> weight row: 16-row groups alternate gate/up so acc pairs line up
    const int wr = ((srow >> 4) & 1) * IDim + col0 + ((srow >> 5) << 4) + (srow & 15);
    const float* bptr = wbase + (size_t)wr * H_DIM + sc_ * 8;
    const bool a0v = srow < rows;
    const bool a1v = (srow + 128) < rows;
    const short* aptr0 = xb + (size_t)toks[srow] * H_DIM + sc_ * 8;
    const short* aptr1 = xb + (size_t)toks[srow + 128] * H_DIM + sc_ * 8;
    const int aoff0 = srow * LDSTRIDE + sc_ * 8;
    const int aoff1 = (srow + 128) * LDSTRIDE + sc_ * 8;
    const int boff  = srow * LDSTRIDE + sc_ * 8;

    f32x4 acc[4][4];
    #pragma unroll
    for (int i = 0; i < 4; ++i)
        #pragma unroll
        for (int j = 0; j < 4; ++j) acc[i][j] = 0.f;

    short8v cA0{}, cA1{};
    if (a0v) cA0 = *(const short8v*)(aptr0);
    if (a1v) cA1 = *(const short8v*)(aptr1);
    float4 cB0 = *(const float4*)(bptr), cB1 = *(const float4*)(bptr + 4);

    int buf = 0;
    for (int k0 = 0; k0 < H_DIM; k0 += 32) {
        short8v nA0{}, nA1{};
        float4 nB0{}, nB1{};
        const int k1 = k0 + 32;
        if (k1 < H_DIM) {
            if (a0v) nA0 = *(const short8v*)(aptr0 + k1);
            if (a1v) nA1 = *(const short8v*)(aptr1 + k1);
            nB0 = *(const float4*)(bptr + k1); nB1 = *(const float4*)(bptr + k1 + 4);
        }
        if (a0v) *(short8v*)&As[buf][aoff0] = cA0;
        if (a1v) *(short8v*)&As[buf][aoff1] = cA1;
        *(uint4v*)&Bs[buf][boff] = pk8bf(cB0, cB1);
        __syncthreads();
        if (wm < mchunks) {
            short8v a_[4], b_[4];
            #pragma unroll
            for (int mt = 0; mt < 4; ++mt)
                a_[mt] = *(const short8v*)&As[buf][(wm * 64 + mt * 16 + lr16) * LDSTRIDE + kc * 8];
            #pragma unroll
            for (int nt = 0; nt < 4; ++nt)
                b_[nt] = *(const short8v*)&Bs[buf][(wn * 64 + nt * 16 + lr16) * LDSTRIDE + kc * 8];
            #pragma unroll
            for (int mt = 0; mt < 4; ++mt)
                #pragma unroll
                for (int nt = 0; nt < 4; ++nt)
                    acc[mt][nt] = __builtin_amdgcn_mfma_f32_16x16x32_bf16(a_[mt], b_[nt], acc[mt][nt], 0, 0, 0);
        }
        buf ^= 1;
        cA0 = nA0; cA1 = nA1; cB0 = nB0; cB1 = nB1;
    }

    if (wm >= mchunks) return;
    #pragma unroll
    for (int mt = 0; mt < 4; ++mt) {
        #pragma unroll
        for (int q = 0; q < 2; ++q) {
            f32x4 g = acc[mt][2 * q], u = acc[mt][2 * q + 1];
            const int colI = col0 + wn * 32 + q * 16 + lr16;
            #pragma unroll
            for (int i = 0; i < 4; ++i) {
                int r = wm * 64 + mt * 16 + kc * 4 + i;
                if (r < ne) {
                    float s = sws[r];
                    short* dst = sh ? (acts + (size_t)(r0 + r) * IS_DIM + colI)
                                    : (act + ((size_t)e * CAP + r) * I_DIM + colI);
                    *dst = f2bf(s * silu_(g[i]) * u[i]);
                }
            }
        }
    }
}

// down-proj + atomic scatter onto zeroed out.  grid (8, MAXTILES)
__global__ __launch_bounds__(512, 2) void down_all_kernel(
    const short* __restrict__ act, const short* __restrict__ acts,
    const float* __restrict__ w_down, const float* __restrict__ w_ds,
    const int* __restrict__ ntiles, const int* __restrict__ tiles,
    const int* __restrict__ slot_token, float* __restrict__ out)
{
    if ((int)blockIdx.y >= *ntiles) return;
    const int e  = tiles[blockIdx.y * 4];
    const int r0 = tiles[blockIdx.y * 4 + 1];
    const int ne = tiles[blockIdx.y * 4 + 2];
    const bool sh = (e < 0);
    const int h0 = blockIdx.x * 128;
    const int mchunks = (ne + 63) >> 6;
    const int rows = mchunks << 6;

    __shared__ __align__(16) short As[2][256 * LDSTRIDE];
    __shared__ __align__(16) short Bs[2][128 * LDSTRIDE];
    __shared__ int toks[256];

    const int tid = threadIdx.x;
    const int lane = tid & 63, wid = tid >> 6;
    const int wm = wid & 3, wn = wid >> 2;
    const int lr16 = lane & 15, kc = lane >> 4;
    const int sc_ = tid & 3, srow = tid >> 2;

    if (tid < 256) {
        if (sh) toks[tid] = r0 + tid;
        else    toks[tid] = (tid < ne) ? slot_token[e * CAP + tid] : 0;
    }
    __syncthreads();

    const int Kdim = sh ? IS_DIM : I_DIM;
    const short* abase = sh ? (acts + (size_t)r0 * IS_DIM) : (act + (size_t)e * CAP * I_DIM);
    const float* wbase = sh ? w_ds : (w_down + (size_t)e * H_DIM * I_DIM);
    const float* bptr  = wbase + (size_t)(h0 + srow) * Kdim + sc_ * 8;
    const bool a0v = srow < rows;
    const bool a1v = (srow + 128) < rows;
    const short* aptr0 = abase + (size_t)srow * Kdim + sc_ * 8;
    const short* aptr1 = abase + (size_t)(srow + 128) * Kdim + sc_ * 8;
    const int aoff0 = srow * LDSTRIDE + sc_ * 8;
    const int aoff1 = (srow + 128) * LDSTRIDE + sc_ * 8;
    const int boff  = srow * LDSTRIDE + sc_ * 8;

    f32x4 acc[4][4];
    #pragma unroll
    for (int i = 0; i < 4; ++i)
        #pragma unroll
        for (int j = 0; j < 4; ++j) acc[i][j] = 0.f;

    short8v cA0{}, cA1{};
    if (a0v) cA0 = *(const short8v*)(aptr0);
    if (a1v) cA1 = *(const short8v*)(aptr1);
    float4 cB0 = *(const float4*)(bptr), cB1 = *(const float4*)(bptr + 4);

    int buf = 0;
    for (int k0 = 0; k0 < Kdim; k0 += 32) {
        short8v nA0{}, nA1{};
        float4 nB0{}, nB1{};
        const int k1 = k0 + 32;
        if (k1 < Kdim) {
            if (a0v) nA0 = *(const short8v*)(aptr0 + k1);
            if (a1v) nA1 = *(const short8v*)(aptr1 + k1);
            nB0 = *(const float4*)(bptr + k1); nB1 = *(const float4*)(bptr + k1 + 4);
        }
        if (a0v) *(short8v*)&As[buf][aoff0] = cA0;
        if (a1v) *(short8v*)&As[buf][aoff1] = cA1;
        *(uint4v*)&Bs[buf][boff] = pk8bf(cB0, cB1);
        __syncthreads();
        if (wm < mchunks) {
            short8v a_[4], b_[4];
            #pragma unroll
            for (int mt = 0; mt < 4; ++mt)
                a_[mt] = *(const short8v*)&As[buf][(wm * 64 + mt * 16 + lr16) * LDSTRIDE + kc * 8];
            #pragma unroll
            for (int nt = 0; nt < 4; ++nt)
                b_[nt] = *(const short8v*)&Bs[buf][(wn * 64 + nt * 16 + lr16) * LDSTRIDE + kc * 8];
            #pragma unroll
            for (int mt = 0; mt < 4; ++mt)
                #pragma unroll
                for (int nt = 0; nt < 4; ++nt)
                    acc[mt][nt] = __builtin_amdgcn_mfma_f32_16x16x32_bf16(a_[mt], b_[nt], acc[mt][nt], 0, 0, 0);
        }
        buf ^= 1;
        cA0 = nA0; cA1 = nA1; cB0 = nB0; cB1 = nB1;
    }

    if (wm >= mchunks) return;
    #pragma unroll
    for (int mt = 0; mt < 4; ++mt) {
        #pragma unroll
        for (int i = 0; i < 4; ++i) {
            int r = wm * 64 + mt * 16 + kc * 4 + i;
            if (r < ne) {
                float* orow = out + (size_t)toks[r] * H_DIM + h0 + wn * 64;
                #pragma unroll
                for (int nt = 0; nt < 4; ++nt)
                    atomicAdd(&orow[nt * 16 + lr16], acc[mt][nt][i]);
            }
        }
    }
}

extern "C" void kernel_launch(void* const* d_in, const int* in_sizes, int n_in,
                              void* d_out, int out_size, void* d_ws, size_t ws_size,
                              hipStream_t stream) {
    const float* x   = (const float*)d_in[0];
    const float* gw  = (const float*)d_in[1];
    const float* eb  = (const float*)d_in[2];
    const float* wgu = (const float*)d_in[3];
    const float* wd  = (const float*)d_in[4];
    const float* wgs = (const float*)d_in[5];
    const float* wds = (const float*)d_in[6];
    float* out = (float*)d_out;
    char* ws = (char*)d_ws;

    int*   cnt    = (int*)(ws + WS_CNT_OFF);
    int*   ntiles = (int*)(ws + WS_NT_OFF);
    int*   tiles  = (int*)(ws + WS_TILE_OFF);
    int*   eidx   = (int*)(ws + WS_EIDX_OFF);
    float* wnorm  = (float*)(ws + WS_WN_OFF);
    int*   stok   = (int*)(ws + WS_STOK_OFF);
    float* sw     = (float*)(ws + WS_SW_OFF);
    short* act    = (short*)(ws + WS_ACT_OFF);
    short* acts   = (short*)(ws + WS_ACTS_OFF);
    short* xb     = (short*)(ws + WS_XB_OFF);

    hipMemsetAsync(out, 0, (size_t)T_TOK * H_DIM * sizeof(float), stream);
    gate_kernel<<<T_TOK, 256, 0, stream>>>(x, gw, eb, eidx, wnorm, xb);
    assign_kernel<<<1, 256, 0, stream>>>(eidx, wnorm, cnt, stok, sw, ntiles, tiles);
    gu_all_kernel<<<dim3(IS_DIM / 64, MAXTILES), 512, 0, stream>>>(
        xb, wgu, wgs, ntiles, tiles, stok, sw, act, acts);
    down_all_kernel<<<dim3(H_DIM / 128, MAXTILES), 512, 0, stream>>>(
        act, acts, wd, wds, ntiles, tiles, stok, out);
}